// Round 15
// baseline (1801.691 us; speedup 1.0000x reference)
//
#include <hip/hip_runtime.h>

// SP_DNN: two fused 1->256->256->256->256 MLPs (sin activations) + strided rowwise dot.
// fp16 MFMA (16x16x32), fp32 accumulate.
//
// R15 = R11 (808us best: depth-2 A reg-prefetch, depth-1 B, 6 interleaved x/t
// phases, wb+layer0 in MFMA shadow, lgkm-only barriers, params in LDS)
// + PER-WAVE K-STAGGER, one variable, zero register cost.
// R14 post-mortem: halving per-CU A-traffic gave no win -> the phase-time
// "MFMA + A-delivery sum" is not a BW ceiling but a CONVOY: after each
// barrier all 4 waves restart at g=0 together, burst 4 simultaneous A-load
// batches into the CU's L1/TA port, stall together on the same vmcnt, fire
// MFMAs together. Fix: wave w iterates gs=(g0+t)&7 with g0=(2w+blkpar)&7 --
// K-accumulation is order-independent, each wave owns its private A-slice
// (channel-split, no duplication unlike R3's fatal row-split). At any
// instant the block's waves sit at 4 different K-positions: loads smooth
// into a stream, and a vmcnt-stalled wave shares its SIMD with one
// mid-MFMA-cluster -> sum -> max.

typedef _Float16 f16x8 __attribute__((ext_vector_type(8)));
typedef _Float16 f16x4 __attribute__((ext_vector_type(4)));
typedef float f32x4 __attribute__((ext_vector_type(4)));

// Swizzled act-buffer byte offset: row m (0..63, 512 B stride), kbyte in
// [0,512). 16B unit index XORed with (m&7): any 8-lane chunk of a B-read
// covers all 32 banks exactly once; writeback/layer0 <=2-way (free).
__device__ __forceinline__ int hswz(int m, int kbyte) {
    return m * 512 + ((((kbyte >> 4) ^ (m & 7)) & 31) << 4) + (kbyte & 15);
}

// Raw workgroup barrier draining LDS ops only; global loads stay in flight.
__device__ __forceinline__ void barrier_lds() {
    asm volatile("s_waitcnt lgkmcnt(0)" ::: "memory");
    __builtin_amdgcn_s_barrier();
}

// ---------------------------------------------------------------------------
// Prepack: 6 matrices W[k][n] (256x256 f32, k-major) -> fp16 A-fragment-major:
// idx = ((((c*2+ks)*16 + nhi)*4 + quad)*16 + ln)*8 + j
//   n = nhi*16+ln, k = c*64 + ks*32 + quad*8 + j
// ---------------------------------------------------------------------------
__global__ void prepack(const float* __restrict__ xW1, const float* __restrict__ xW2,
                        const float* __restrict__ xW3, const float* __restrict__ tW1,
                        const float* __restrict__ tW2, const float* __restrict__ tW3,
                        _Float16* __restrict__ dst)
{
    int g = blockIdx.x * 256 + threadIdx.x;   // 6*65536 threads exactly
    int L = g >> 16;
    int r = g & 65535;
    int j    = r & 7;
    int ln   = (r >> 3) & 15;
    int quad = (r >> 7) & 3;
    int nhi  = (r >> 9) & 15;
    int ks   = (r >> 13) & 1;
    int c    = (r >> 14) & 3;
    const float* W;
    switch (L) {
        case 0: W = xW1; break;
        case 1: W = xW2; break;
        case 2: W = xW3; break;
        case 3: W = tW1; break;
        case 4: W = tW2; break;
        default: W = tW3; break;
    }
    int n = nhi * 16 + ln;
    int k = c * 64 + ks * 32 + quad * 8 + j;
    dst[g] = (_Float16)W[k * 256 + n];
}

// ---------------------------------------------------------------------------
// Main fused kernel. Block = 256 threads (4 waves), tile = 64 rows.
// Wave w owns out-channels [w*64, w*64+64) in every 256->256 layer.
// ---------------------------------------------------------------------------

__device__ __forceinline__ void layer0_scalar(
    float xv, const float* __restrict__ W0, const float* __restrict__ b0,
    _Float16* __restrict__ hb, int tid)
{
    int m = tid >> 2;        // 64 rows, 4 threads per row
    int q = tid & 3;
#pragma unroll
    for (int g = 0; g < 8; ++g) {
        int n0 = g * 32 + q * 8;        // 4 q-addresses -> 4 distinct banks
        f16x8 hv;
#pragma unroll
        for (int e = 0; e < 8; ++e) {
            float z = fmaf(xv, W0[n0 + e], b0[n0 + e]);
            hv[e] = (_Float16)__sinf(z);
        }
        *(f16x8*)((char*)hb + hswz(m, n0 * 2)) = hv;
    }
}

// One GEMM phase: acc = Wl x rb, iterating gs = (g0+t)&7, t = 0..7.
// A: afr[2][4] depth-2 register pipeline (refill buf[t&1] for t+2 after last
//    use; t=6/7 load Wnext's (g0)/(g0+1) -- in flight across the barrier).
// B: bfr[2][4] depth-1 LDS pipeline (issue t+1's ds_reads before t's MFMAs).
// MODE 1: slice the OTHER MLP's writeback sin(wacc+bias[LDS]) -> wb_lds,
//         2 of 16 fragments per t (s = gs*2+jo covers all 16 over 8 t's).
// MODE 2: slice layer0_t, one 8-channel group per t (n0 = gs*32+q*8).
template<int MODE>   // 0 plain, 1 writeback, 2 layer0-slice
__device__ __forceinline__ void gemm_phase(
    const _Float16* __restrict__ Wl,
    const _Float16* __restrict__ Wnext,    // nullptr at the end
    const _Float16* __restrict__ rb,       // LDS read buffer (activations)
    f32x4 acc[4][4], f16x8 afr[2][4],
    f32x4 wacc[4][4],                      // MODE 1: prev phase's acc
    const float* __restrict__ wbias,       // MODE 1: LDS bias for wacc
    _Float16* __restrict__ wb_lds,         // MODE 1/2: LDS write target
    float xv,                              // MODE 2: scalar input
    const float* __restrict__ W0,          // MODE 2: LDS 1->256 weights
    const float* __restrict__ b0,          // MODE 2: LDS bias
    int tid, int lane, int ln, int quad, int wave, int g0)
{
    f32x4 zero = {0.f, 0.f, 0.f, 0.f};
#pragma unroll
    for (int i = 0; i < 4; ++i)
#pragma unroll
        for (int j = 0; j < 4; ++j)
            acc[i][j] = zero;

    const _Float16* abase = Wl + wave * 2048 + lane * 8;

    f16x8 bfr[2][4];
    {
        const int gs0 = g0 & 7;
#pragma unroll
        for (int j = 0; j < 4; ++j)      // B prologue: t=0 -> buf0
            bfr[0][j] = *(const f16x8*)((const char*)rb +
                                        hswz(16 * j + ln, gs0 * 64 + quad * 16));
    }

#pragma unroll
    for (int t = 0; t < 8; ++t) {
        const int gs = (g0 + t) & 7;
        if (t < 7) {                     // issue t+1's B reads before t's MFMAs
            const int gs1 = (g0 + t + 1) & 7;
#pragma unroll
            for (int j = 0; j < 4; ++j)
                bfr[(t + 1) & 1][j] = *(const f16x8*)((const char*)rb +
                                 hswz(16 * j + ln, gs1 * 64 + quad * 16));
        }

        __builtin_amdgcn_s_setprio(1);
#pragma unroll
        for (int i = 0; i < 4; ++i)
#pragma unroll
            for (int j = 0; j < 4; ++j)
                acc[i][j] = __builtin_amdgcn_mfma_f32_16x16x32_f16(
                    afr[t & 1][i], bfr[t & 1][j], acc[i][j], 0, 0, 0);
        __builtin_amdgcn_s_setprio(0);

        // A refill buf[t&1] for t+2 (program-order after its last MFMA use);
        // t=6/7 chain to the NEXT phase's first two K-groups (g0, g0+1).
        if (t < 6) {
            const int gs2 = (g0 + t + 2) & 7;
#pragma unroll
            for (int i = 0; i < 4; ++i)
                afr[t & 1][i] = *(const f16x8*)(abase + gs2 * 8192 + i * 512);
        } else if (Wnext) {
            const int gs2 = (g0 + t + 2) & 7;   // t=6 -> g0, t=7 -> g0+1
#pragma unroll
            for (int i = 0; i < 4; ++i)
                afr[t & 1][i] = *(const f16x8*)(Wnext + gs2 * 8192 +
                                                wave * 2048 + lane * 8 + i * 512);
        }

        if (MODE == 1) {                 // writeback slice: frag wi, 2 wj's
            const int wi = gs >> 1;
            const int nb = wave * 64 + 16 * wi + quad * 4;
            f32x4 bv = *(const f32x4*)&wbias[nb];            // LDS, 4-addr bcast
#pragma unroll
            for (int jo = 0; jo < 2; ++jo) {
                const int wj = (gs & 1) * 2 + jo;
                f16x4 hv;
                hv[0] = (_Float16)__sinf(wacc[wi][wj][0] + bv[0]);
                hv[1] = (_Float16)__sinf(wacc[wi][wj][1] + bv[1]);
                hv[2] = (_Float16)__sinf(wacc[wi][wj][2] + bv[2]);
                hv[3] = (_Float16)__sinf(wacc[wi][wj][3] + bv[3]);
                *(f16x4*)((char*)wb_lds + hswz(16 * wj + ln, nb * 2)) = hv;
            }
        } else if (MODE == 2) {          // layer0 slice: one 8-ch group
            const int m = tid >> 2, q = tid & 3;
            const int n0 = gs * 32 + q * 8;
            f16x8 hv;
#pragma unroll
            for (int e = 0; e < 8; ++e) {
                float z = fmaf(xv, W0[n0 + e], b0[n0 + e]);
                hv[e] = (_Float16)__sinf(z);
            }
            *(f16x8*)((char*)wb_lds + hswz(m, n0 * 2)) = hv;
        }
    }
}

__global__ __launch_bounds__(256, 2)
void mlp_fused(const float* __restrict__ x,
               const float* __restrict__ xW0, const float* __restrict__ xb0,
               const float* __restrict__ xb1, const float* __restrict__ xb2,
               const float* __restrict__ xb3,
               const float* __restrict__ tW0, const float* __restrict__ tb0,
               const float* __restrict__ tb1, const float* __restrict__ tb2,
               const float* __restrict__ tb3,
               const _Float16* __restrict__ Wp,
               float* __restrict__ out)
{
    __shared__ __align__(16) _Float16 hbuf[2][64 * 256];   // [0]=x acts, [1]=t acts
    __shared__ __align__(16) float    params[10 * 256];    // 10 KB small params

    const int tid = threadIdx.x;
    const int lane = tid & 63;
    const int wave = tid >> 6;       // 0..3
    const int ln = lane & 15;
    const int quad = lane >> 4;
    const int row0 = blockIdx.x * 64;
    // Per-wave K-stagger: 4 in-block phases + block-parity offset.
    const int g0 = (wave * 2 + (blockIdx.x & 1)) & 7;

    // Preload all small params to LDS.
    // segs: 0 xW0, 1 xb0, 2 tW0, 3 tb0, 4 xb1, 5 xb2, 6 xb3, 7 tb1, 8 tb2, 9 tb3
    {
        const float* psrc[10] = {xW0, xb0, tW0, tb0, xb1, xb2, xb3, tb1, tb2, tb3};
#pragma unroll
        for (int s = 0; s < 10; ++s)
            params[s * 256 + tid] = psrc[s][tid];
    }
    const float2 xv2 = ((const float2*)x)[row0 + (tid >> 2)];  // both MLP inputs

    f32x4 xacc[4][4], tacc[4][4];    // 128 AGPR
    f16x8 afr[2][4];                 // A-fragment register double-buffer (32 VGPR)

    // Prologue: xW1 (g0) -> buf0, (g0+1) -> buf1; land during layer0_x.
#pragma unroll
    for (int s = 0; s < 2; ++s) {
        const int gs = (g0 + s) & 7;
#pragma unroll
        for (int i = 0; i < 4; ++i)
            afr[s][i] = *(const f16x8*)(Wp + gs * 8192 + wave * 2048 +
                                        lane * 8 + i * 512);
    }
    barrier_lds();                    // params visible to all waves

    // ----- layer0_x -----
    layer0_scalar(xv2.x, &params[0], &params[256], hbuf[0], tid);
    barrier_lds();                    // x acts visible

    // ----- 6 alternating GEMM phases -----
    // P1: x1; layer0_t sliced in -> hbuf[1]
    gemm_phase<2>(Wp + 0 * 65536, Wp + 3 * 65536, hbuf[0], xacc, afr,
                  nullptr, nullptr, hbuf[1],
                  xv2.y, &params[2 * 256], &params[3 * 256],
                  tid, lane, ln, quad, wave, g0);
    barrier_lds();
    // P2: t1 || wb_x1 -> hbuf[0]
    gemm_phase<1>(Wp + 3 * 65536, Wp + 1 * 65536, hbuf[1], tacc, afr,
                  xacc, &params[4 * 256], hbuf[0],
                  0.f, nullptr, nullptr, tid, lane, ln, quad, wave, g0);
    barrier_lds();
    // P3: x2 || wb_t1 -> hbuf[1]
    gemm_phase<1>(Wp + 1 * 65536, Wp + 4 * 65536, hbuf[0], xacc, afr,
                  tacc, &params[7 * 256], hbuf[1],
                  0.f, nullptr, nullptr, tid, lane, ln, quad, wave, g0);
    barrier_lds();
    // P4: t2 || wb_x2 -> hbuf[0]
    gemm_phase<1>(Wp + 4 * 65536, Wp + 2 * 65536, hbuf[1], tacc, afr,
                  xacc, &params[5 * 256], hbuf[0],
                  0.f, nullptr, nullptr, tid, lane, ln, quad, wave, g0);
    barrier_lds();
    // P5: x3 || wb_t2 -> hbuf[1]
    gemm_phase<1>(Wp + 2 * 65536, Wp + 5 * 65536, hbuf[0], xacc, afr,
                  tacc, &params[8 * 256], hbuf[1],
                  0.f, nullptr, nullptr, tid, lane, ln, quad, wave, g0);
    barrier_lds();
    // P6: t3
    gemm_phase<0>(Wp + 5 * 65536, nullptr, hbuf[1], tacc, afr,
                  nullptr, nullptr, nullptr,
                  0.f, nullptr, nullptr, tid, lane, ln, quad, wave, g0);

    // ----- combine: even/odd strided dot, fp32 -----
    const float* xb3l = &params[6 * 256];
    const float* tb3l = &params[9 * 256];
    float ev[4] = {0.f, 0.f, 0.f, 0.f};
    float od[4] = {0.f, 0.f, 0.f, 0.f};
#pragma unroll
    for (int i = 0; i < 4; ++i) {
        int nb = wave * 64 + 16 * i + quad * 4;
        f32x4 xb = *(const f32x4*)&xb3l[nb];
        f32x4 tb = *(const f32x4*)&tb3l[nb];
#pragma unroll
        for (int j = 0; j < 4; ++j) {
            float a0 = xacc[i][j][0] + xb[0], c0 = tacc[i][j][0] + tb[0];
            float a1 = xacc[i][j][1] + xb[1], c1 = tacc[i][j][1] + tb[1];
            float a2 = xacc[i][j][2] + xb[2], c2 = tacc[i][j][2] + tb[2];
            float a3 = xacc[i][j][3] + xb[3], c3 = tacc[i][j][3] + tb[3];
            ev[j] += a0 * c0 + a2 * c2;      // channel parity = reg index parity
            od[j] += a1 * c1 + a3 * c3;
        }
    }
#pragma unroll
    for (int j = 0; j < 4; ++j) {            // reduce over the 4 quads
        ev[j] += __shfl_xor(ev[j], 16, 64);
        ev[j] += __shfl_xor(ev[j], 32, 64);
        od[j] += __shfl_xor(od[j], 16, 64);
        od[j] += __shfl_xor(od[j], 32, 64);
    }

    // hbuf[0] dead: its last readers (P5) all passed the P5->P6 barrier.
    float* red = (float*)hbuf[0];
    if (lane < 16) {
#pragma unroll
        for (int j = 0; j < 4; ++j) {
            red[wave * 128 + j * 32 + lane * 2 + 0] = ev[j];
            red[wave * 128 + j * 32 + lane * 2 + 1] = od[j];
        }
    }
    __syncthreads();
    if (tid < 128) {                         // sum the 4 wave partials; coalesced store
        int jj = tid >> 5, m16 = (tid >> 1) & 15, p = tid & 1;
        int base = jj * 32 + m16 * 2 + p;
        float s = red[base] + red[128 + base] + red[256 + base] + red[384 + base];
        out[(row0 + 16 * jj + m16) * 2 + p] = s;
    }
}

// ---------------------------------------------------------------------------
extern "C" void kernel_launch(void* const* d_in, const int* in_sizes, int n_in,
                              void* d_out, int out_size, void* d_ws, size_t ws_size,
                              hipStream_t stream)
{
    const float* x   = (const float*)d_in[0];
    const float* xW0 = (const float*)d_in[1];
    const float* xb0 = (const float*)d_in[2];
    const float* xW1 = (const float*)d_in[3];
    const float* xb1 = (const float*)d_in[4];
    const float* xW2 = (const float*)d_in[5];
    const float* xb2 = (const float*)d_in[6];
    const float* xW3 = (const float*)d_in[7];
    const float* xb3 = (const float*)d_in[8];
    const float* tW0 = (const float*)d_in[9];
    const float* tb0 = (const float*)d_in[10];
    const float* tW1 = (const float*)d_in[11];
    const float* tb1 = (const float*)d_in[12];
    const float* tW2 = (const float*)d_in[13];
    const float* tb2 = (const float*)d_in[14];
    const float* tW3 = (const float*)d_in[15];
    const float* tb3 = (const float*)d_in[16];

    _Float16* Wp = (_Float16*)d_ws;          // 6*65536 fp16 = 768 KB
    const int N = in_sizes[0] / 2;           // 1,000,000 (divisible by 64)

    prepack<<<1536, 256, 0, stream>>>(xW1, xW2, xW3, tW1, tW2, tW3, Wp);
    mlp_fused<<<N / 64, 256, 0, stream>>>(x, xW0, xb0, xb1, xb2, xb3,
                                          tW0, tb0, tb1, tb2, tb3,
                                          Wp, (float*)d_out);
}

// Round 16
// 814.492 us; speedup vs baseline: 2.2120x; 2.2120x over previous
//
#include <hip/hip_runtime.h>

// SP_DNN: two fused 1->256->256->256->256 MLPs (sin activations) + strided rowwise dot.
// fp16 MFMA (16x16x32), fp32 accumulate.
//
// R16 = R15 (per-wave K-stagger) with the rule-#20 violation fixed. R15's
// 6 GB scratch traffic: the wb slice indexed wacc[gs>>1][..] with gs runtime
// (g0 is wave-dependent) -> runtime-indexed ext_vector array -> compiler
// demoted the whole accumulator to scratch. Fix: slice by the UNROLL COUNTER
// t (compile-time): wb frag (t>>1, (t&1)*2+jo), layer0 group n0=t*32+q*8.
// The slicing never needed to follow the K-group -- it is an arbitrary 8-way
// split of independent work. Runtime gs now appears ONLY in addresses.
// This is the clean test of the convoy hypothesis: wave w iterates
// gs=(g0+t)&7, g0=(2w+blkpar)&7 -> the block's 4 waves sit at 4 different
// K-positions; A-load bursts smooth into a stream; a vmcnt-stalled wave
// shares its SIMD with one mid-MFMA-cluster.
// Base structure (R11, 808us): depth-2 A reg-prefetch chaining across
// phases, depth-1 B, 6 interleaved x/t phases, wb+layer0 in MFMA shadow,
// lgkm-only barriers, params in LDS, 2 blk/CU.

typedef _Float16 f16x8 __attribute__((ext_vector_type(8)));
typedef _Float16 f16x4 __attribute__((ext_vector_type(4)));
typedef float f32x4 __attribute__((ext_vector_type(4)));

// Swizzled act-buffer byte offset: row m (0..63, 512 B stride), kbyte in
// [0,512). 16B unit index XORed with (m&7): any 8-lane chunk of a B-read
// covers all 32 banks exactly once; writeback/layer0 <=2-way (free).
__device__ __forceinline__ int hswz(int m, int kbyte) {
    return m * 512 + ((((kbyte >> 4) ^ (m & 7)) & 31) << 4) + (kbyte & 15);
}

// Raw workgroup barrier draining LDS ops only; global loads stay in flight.
__device__ __forceinline__ void barrier_lds() {
    asm volatile("s_waitcnt lgkmcnt(0)" ::: "memory");
    __builtin_amdgcn_s_barrier();
}

// ---------------------------------------------------------------------------
// Prepack: 6 matrices W[k][n] (256x256 f32, k-major) -> fp16 A-fragment-major:
// idx = ((((c*2+ks)*16 + nhi)*4 + quad)*16 + ln)*8 + j
//   n = nhi*16+ln, k = c*64 + ks*32 + quad*8 + j
// ---------------------------------------------------------------------------
__global__ void prepack(const float* __restrict__ xW1, const float* __restrict__ xW2,
                        const float* __restrict__ xW3, const float* __restrict__ tW1,
                        const float* __restrict__ tW2, const float* __restrict__ tW3,
                        _Float16* __restrict__ dst)
{
    int g = blockIdx.x * 256 + threadIdx.x;   // 6*65536 threads exactly
    int L = g >> 16;
    int r = g & 65535;
    int j    = r & 7;
    int ln   = (r >> 3) & 15;
    int quad = (r >> 7) & 3;
    int nhi  = (r >> 9) & 15;
    int ks   = (r >> 13) & 1;
    int c    = (r >> 14) & 3;
    const float* W;
    switch (L) {
        case 0: W = xW1; break;
        case 1: W = xW2; break;
        case 2: W = xW3; break;
        case 3: W = tW1; break;
        case 4: W = tW2; break;
        default: W = tW3; break;
    }
    int n = nhi * 16 + ln;
    int k = c * 64 + ks * 32 + quad * 8 + j;
    dst[g] = (_Float16)W[k * 256 + n];
}

// ---------------------------------------------------------------------------
// Main fused kernel. Block = 256 threads (4 waves), tile = 64 rows.
// Wave w owns out-channels [w*64, w*64+64) in every 256->256 layer.
// ---------------------------------------------------------------------------

__device__ __forceinline__ void layer0_scalar(
    float xv, const float* __restrict__ W0, const float* __restrict__ b0,
    _Float16* __restrict__ hb, int tid)
{
    int m = tid >> 2;        // 64 rows, 4 threads per row
    int q = tid & 3;
#pragma unroll
    for (int g = 0; g < 8; ++g) {
        int n0 = g * 32 + q * 8;        // 4 q-addresses -> 4 distinct banks
        f16x8 hv;
#pragma unroll
        for (int e = 0; e < 8; ++e) {
            float z = fmaf(xv, W0[n0 + e], b0[n0 + e]);
            hv[e] = (_Float16)__sinf(z);
        }
        *(f16x8*)((char*)hb + hswz(m, n0 * 2)) = hv;
    }
}

// One GEMM phase: acc = Wl x rb, iterating gs = (g0+t)&7, t = 0..7.
// A: afr[2][4] depth-2 register pipeline (refill buf[t&1] for t+2 after last
//    use; t=6/7 load Wnext's (g0)/(g0+1) -- in flight across the barrier).
// B: bfr[2][4] depth-1 LDS pipeline (issue t+1's ds_reads before t's MFMAs).
// MODE 1: slice the OTHER MLP's writeback sin(wacc+bias[LDS]) -> wb_lds,
//         2 of 16 fragments per t, keyed by t (COMPILE-TIME: rule #20).
// MODE 2: slice layer0_t, one 8-channel group per t (n0 = t*32+q*8).
template<int MODE>   // 0 plain, 1 writeback, 2 layer0-slice
__device__ __forceinline__ void gemm_phase(
    const _Float16* __restrict__ Wl,
    const _Float16* __restrict__ Wnext,    // nullptr at the end
    const _Float16* __restrict__ rb,       // LDS read buffer (activations)
    f32x4 acc[4][4], f16x8 afr[2][4],
    f32x4 wacc[4][4],                      // MODE 1: prev phase's acc
    const float* __restrict__ wbias,       // MODE 1: LDS bias for wacc
    _Float16* __restrict__ wb_lds,         // MODE 1/2: LDS write target
    float xv,                              // MODE 2: scalar input
    const float* __restrict__ W0,          // MODE 2: LDS 1->256 weights
    const float* __restrict__ b0,          // MODE 2: LDS bias
    int tid, int lane, int ln, int quad, int wave, int g0)
{
    f32x4 zero = {0.f, 0.f, 0.f, 0.f};
#pragma unroll
    for (int i = 0; i < 4; ++i)
#pragma unroll
        for (int j = 0; j < 4; ++j)
            acc[i][j] = zero;

    const _Float16* abase = Wl + wave * 2048 + lane * 8;

    f16x8 bfr[2][4];
    {
        const int gs0 = g0 & 7;
#pragma unroll
        for (int j = 0; j < 4; ++j)      // B prologue: t=0 -> buf0
            bfr[0][j] = *(const f16x8*)((const char*)rb +
                                        hswz(16 * j + ln, gs0 * 64 + quad * 16));
    }

#pragma unroll
    for (int t = 0; t < 8; ++t) {
        if (t < 7) {                     // issue t+1's B reads before t's MFMAs
            const int gs1 = (g0 + t + 1) & 7;   // runtime ADDRESS only
#pragma unroll
            for (int j = 0; j < 4; ++j)
                bfr[(t + 1) & 1][j] = *(const f16x8*)((const char*)rb +
                                 hswz(16 * j + ln, gs1 * 64 + quad * 16));
        }

        __builtin_amdgcn_s_setprio(1);
#pragma unroll
        for (int i = 0; i < 4; ++i)
#pragma unroll
            for (int j = 0; j < 4; ++j)
                acc[i][j] = __builtin_amdgcn_mfma_f32_16x16x32_f16(
                    afr[t & 1][i], bfr[t & 1][j], acc[i][j], 0, 0, 0);
        __builtin_amdgcn_s_setprio(0);

        // A refill buf[t&1] for t+2 (program-order after its last MFMA use);
        // t=6/7 chain to the NEXT phase's first two K-groups (g0, g0+1).
        if (t < 6) {
            const int gs2 = (g0 + t + 2) & 7;   // runtime ADDRESS only
#pragma unroll
            for (int i = 0; i < 4; ++i)
                afr[t & 1][i] = *(const f16x8*)(abase + gs2 * 8192 + i * 512);
        } else if (Wnext) {
            const int gs2 = (g0 + t + 2) & 7;   // t=6 -> g0, t=7 -> g0+1
#pragma unroll
            for (int i = 0; i < 4; ++i)
                afr[t & 1][i] = *(const f16x8*)(Wnext + gs2 * 8192 +
                                                wave * 2048 + lane * 8 + i * 512);
        }

        if (MODE == 1) {                 // wb slice keyed by t: COMPILE-TIME idx
            const int wi = t >> 1;       // static after unroll (rule #20)
            const int nb = wave * 64 + 16 * wi + quad * 4;
            f32x4 bv = *(const f32x4*)&wbias[nb];            // LDS, 4-addr bcast
#pragma unroll
            for (int jo = 0; jo < 2; ++jo) {
                const int wj = (t & 1) * 2 + jo;             // static
                f16x4 hv;
                hv[0] = (_Float16)__sinf(wacc[wi][wj][0] + bv[0]);
                hv[1] = (_Float16)__sinf(wacc[wi][wj][1] + bv[1]);
                hv[2] = (_Float16)__sinf(wacc[wi][wj][2] + bv[2]);
                hv[3] = (_Float16)__sinf(wacc[wi][wj][3] + bv[3]);
                *(f16x4*)((char*)wb_lds + hswz(16 * wj + ln, nb * 2)) = hv;
            }
        } else if (MODE == 2) {          // layer0 slice keyed by t
            const int m = tid >> 2, q = tid & 3;
            const int n0 = t * 32 + q * 8;                   // static t
            f16x8 hv;
#pragma unroll
            for (int e = 0; e < 8; ++e) {
                float z = fmaf(xv, W0[n0 + e], b0[n0 + e]);
                hv[e] = (_Float16)__sinf(z);
            }
            *(f16x8*)((char*)wb_lds + hswz(m, n0 * 2)) = hv;
        }
    }
}

__global__ __launch_bounds__(256, 2)
void mlp_fused(const float* __restrict__ x,
               const float* __restrict__ xW0, const float* __restrict__ xb0,
               const float* __restrict__ xb1, const float* __restrict__ xb2,
               const float* __restrict__ xb3,
               const float* __restrict__ tW0, const float* __restrict__ tb0,
               const float* __restrict__ tb1, const float* __restrict__ tb2,
               const float* __restrict__ tb3,
               const _Float16* __restrict__ Wp,
               float* __restrict__ out)
{
    __shared__ __align__(16) _Float16 hbuf[2][64 * 256];   // [0]=x acts, [1]=t acts
    __shared__ __align__(16) float    params[10 * 256];    // 10 KB small params

    const int tid = threadIdx.x;
    const int lane = tid & 63;
    const int wave = tid >> 6;       // 0..3
    const int ln = lane & 15;
    const int quad = lane >> 4;
    const int row0 = blockIdx.x * 64;
    // Per-wave K-stagger: 4 in-block phases + block-parity offset.
    const int g0 = (wave * 2 + (blockIdx.x & 1)) & 7;

    // Preload all small params to LDS.
    // segs: 0 xW0, 1 xb0, 2 tW0, 3 tb0, 4 xb1, 5 xb2, 6 xb3, 7 tb1, 8 tb2, 9 tb3
    {
        const float* psrc[10] = {xW0, xb0, tW0, tb0, xb1, xb2, xb3, tb1, tb2, tb3};
#pragma unroll
        for (int s = 0; s < 10; ++s)
            params[s * 256 + tid] = psrc[s][tid];
    }
    const float2 xv2 = ((const float2*)x)[row0 + (tid >> 2)];  // both MLP inputs

    f32x4 xacc[4][4], tacc[4][4];    // 128 AGPR
    f16x8 afr[2][4];                 // A-fragment register double-buffer (32 VGPR)

    // Prologue: xW1 (g0) -> buf0, (g0+1) -> buf1; land during layer0_x.
#pragma unroll
    for (int s = 0; s < 2; ++s) {
        const int gs = (g0 + s) & 7;
#pragma unroll
        for (int i = 0; i < 4; ++i)
            afr[s][i] = *(const f16x8*)(Wp + gs * 8192 + wave * 2048 +
                                        lane * 8 + i * 512);
    }
    barrier_lds();                    // params visible to all waves

    // ----- layer0_x -----
    layer0_scalar(xv2.x, &params[0], &params[256], hbuf[0], tid);
    barrier_lds();                    // x acts visible

    // ----- 6 alternating GEMM phases -----
    // P1: x1; layer0_t sliced in -> hbuf[1]
    gemm_phase<2>(Wp + 0 * 65536, Wp + 3 * 65536, hbuf[0], xacc, afr,
                  nullptr, nullptr, hbuf[1],
                  xv2.y, &params[2 * 256], &params[3 * 256],
                  tid, lane, ln, quad, wave, g0);
    barrier_lds();
    // P2: t1 || wb_x1 -> hbuf[0]
    gemm_phase<1>(Wp + 3 * 65536, Wp + 1 * 65536, hbuf[1], tacc, afr,
                  xacc, &params[4 * 256], hbuf[0],
                  0.f, nullptr, nullptr, tid, lane, ln, quad, wave, g0);
    barrier_lds();
    // P3: x2 || wb_t1 -> hbuf[1]
    gemm_phase<1>(Wp + 1 * 65536, Wp + 4 * 65536, hbuf[0], xacc, afr,
                  tacc, &params[7 * 256], hbuf[1],
                  0.f, nullptr, nullptr, tid, lane, ln, quad, wave, g0);
    barrier_lds();
    // P4: t2 || wb_x2 -> hbuf[0]
    gemm_phase<1>(Wp + 4 * 65536, Wp + 2 * 65536, hbuf[1], tacc, afr,
                  xacc, &params[5 * 256], hbuf[0],
                  0.f, nullptr, nullptr, tid, lane, ln, quad, wave, g0);
    barrier_lds();
    // P5: x3 || wb_t2 -> hbuf[1]
    gemm_phase<1>(Wp + 2 * 65536, Wp + 5 * 65536, hbuf[0], xacc, afr,
                  tacc, &params[8 * 256], hbuf[1],
                  0.f, nullptr, nullptr, tid, lane, ln, quad, wave, g0);
    barrier_lds();
    // P6: t3
    gemm_phase<0>(Wp + 5 * 65536, nullptr, hbuf[1], tacc, afr,
                  nullptr, nullptr, nullptr,
                  0.f, nullptr, nullptr, tid, lane, ln, quad, wave, g0);

    // ----- combine: even/odd strided dot, fp32 -----
    const float* xb3l = &params[6 * 256];
    const float* tb3l = &params[9 * 256];
    float ev[4] = {0.f, 0.f, 0.f, 0.f};
    float od[4] = {0.f, 0.f, 0.f, 0.f};
#pragma unroll
    for (int i = 0; i < 4; ++i) {
        int nb = wave * 64 + 16 * i + quad * 4;
        f32x4 xb = *(const f32x4*)&xb3l[nb];
        f32x4 tb = *(const f32x4*)&tb3l[nb];
#pragma unroll
        for (int j = 0; j < 4; ++j) {
            float a0 = xacc[i][j][0] + xb[0], c0 = tacc[i][j][0] + tb[0];
            float a1 = xacc[i][j][1] + xb[1], c1 = tacc[i][j][1] + tb[1];
            float a2 = xacc[i][j][2] + xb[2], c2 = tacc[i][j][2] + tb[2];
            float a3 = xacc[i][j][3] + xb[3], c3 = tacc[i][j][3] + tb[3];
            ev[j] += a0 * c0 + a2 * c2;      // channel parity = reg index parity
            od[j] += a1 * c1 + a3 * c3;
        }
    }
#pragma unroll
    for (int j = 0; j < 4; ++j) {            // reduce over the 4 quads
        ev[j] += __shfl_xor(ev[j], 16, 64);
        ev[j] += __shfl_xor(ev[j], 32, 64);
        od[j] += __shfl_xor(od[j], 16, 64);
        od[j] += __shfl_xor(od[j], 32, 64);
    }

    // hbuf[0] dead: its last readers (P5) all passed the P5->P6 barrier.
    float* red = (float*)hbuf[0];
    if (lane < 16) {
#pragma unroll
        for (int j = 0; j < 4; ++j) {
            red[wave * 128 + j * 32 + lane * 2 + 0] = ev[j];
            red[wave * 128 + j * 32 + lane * 2 + 1] = od[j];
        }
    }
    __syncthreads();
    if (tid < 128) {                         // sum the 4 wave partials; coalesced store
        int jj = tid >> 5, m16 = (tid >> 1) & 15, p = tid & 1;
        int base = jj * 32 + m16 * 2 + p;
        float s = red[base] + red[128 + base] + red[256 + base] + red[384 + base];
        out[(row0 + 16 * jj + m16) * 2 + p] = s;
    }
}

// ---------------------------------------------------------------------------
extern "C" void kernel_launch(void* const* d_in, const int* in_sizes, int n_in,
                              void* d_out, int out_size, void* d_ws, size_t ws_size,
                              hipStream_t stream)
{
    const float* x   = (const float*)d_in[0];
    const float* xW0 = (const float*)d_in[1];
    const float* xb0 = (const float*)d_in[2];
    const float* xW1 = (const float*)d_in[3];
    const float* xb1 = (const float*)d_in[4];
    const float* xW2 = (const float*)d_in[5];
    const float* xb2 = (const float*)d_in[6];
    const float* xW3 = (const float*)d_in[7];
    const float* xb3 = (const float*)d_in[8];
    const float* tW0 = (const float*)d_in[9];
    const float* tb0 = (const float*)d_in[10];
    const float* tW1 = (const float*)d_in[11];
    const float* tb1 = (const float*)d_in[12];
    const float* tW2 = (const float*)d_in[13];
    const float* tb2 = (const float*)d_in[14];
    const float* tW3 = (const float*)d_in[15];
    const float* tb3 = (const float*)d_in[16];

    _Float16* Wp = (_Float16*)d_ws;          // 6*65536 fp16 = 768 KB
    const int N = in_sizes[0] / 2;           // 1,000,000 (divisible by 64)

    prepack<<<1536, 256, 0, stream>>>(xW1, xW2, xW3, tW1, tW2, tW3, Wp);
    mlp_fused<<<N / 64, 256, 0, stream>>>(x, xW0, xb0, xb1, xb2, xb3,
                                          tW0, tb0, tb1, tb2, tb3,
                                          Wp, (float*)d_out);
}